// Round 5
// baseline (555.986 us; speedup 1.0000x reference)
//
#include <hip/hip_runtime.h>

// Problem constants (fixed by reference)
#define N_SRC   100000
#define N_DSTC  50000
#define N_EDGES 1000000
#define DIM     64
#define NCLS    64

#define SCAN_BPB 256                                   // bins per scan block
#define SCAN_NB  ((N_DSTC + SCAN_BPB - 1) / SCAN_BPB)  // 196

// ws layout (4-byte slots):
//   hist       [0, 50000)            int   (zeroed)
//   colsum     [50000, 50064)        float (zeroed)
//   regacc     [50064]               float (zeroed)
//   done       [50065]               int   (zeroed)
//   blockSums  [50066, 50066+196)    int   (fully written by scan_local)
//   cursor     [50262, 100262)       int   (fully written by scan chain)
//   sorted_src [100262, 1100262)     int   (fully written by reorder)

// ---------------------------------------------------------------------------
// K1: histogram of dst. int4-vectorized: 4 edges/thread.
__global__ __launch_bounds__(256) void hist_kernel(
    const int4* __restrict__ dst4, int* __restrict__ hist) {
  int i = blockIdx.x * blockDim.x + threadIdx.x;
  if (i < N_EDGES / 4) {
    int4 d = dst4[i];
    atomicAdd(&hist[d.x], 1);
    atomicAdd(&hist[d.y], 1);
    atomicAdd(&hist[d.z], 1);
    atomicAdd(&hist[d.w], 1);
  }
}

// ---------------------------------------------------------------------------
// K2a: per-block exclusive scan of 256 bins; emit block totals.
__global__ __launch_bounds__(256) void scan_local(
    const int* __restrict__ hist, int* __restrict__ cursor,
    int* __restrict__ blockSums) {
  __shared__ int A[256], B[256];
  const int b = blockIdx.x, t = threadIdx.x;
  const int g = b * SCAN_BPB + t;
  int v = (g < N_DSTC) ? hist[g] : 0;
  A[t] = v;
  __syncthreads();
  int* cur = A; int* nxt = B;
  for (int off = 1; off < 256; off <<= 1) {
    int s = cur[t] + ((t >= off) ? cur[t - off] : 0);
    nxt[t] = s;
    __syncthreads();
    int* tmp = cur; cur = nxt; nxt = tmp;
  }
  if (g < N_DSTC) cursor[g] = cur[t] - v;   // exclusive
  if (t == 255) blockSums[b] = cur[255];
}

// K2b: single-block exclusive scan of the 196 block totals (in place).
__global__ __launch_bounds__(256) void scan_top(int* __restrict__ blockSums) {
  __shared__ int A[256], B[256];
  const int t = threadIdx.x;
  int v = (t < SCAN_NB) ? blockSums[t] : 0;
  A[t] = v;
  __syncthreads();
  int* cur = A; int* nxt = B;
  for (int off = 1; off < 256; off <<= 1) {
    int s = cur[t] + ((t >= off) ? cur[t - off] : 0);
    nxt[t] = s;
    __syncthreads();
    int* tmp = cur; cur = nxt; nxt = tmp;
  }
  if (t < SCAN_NB) blockSums[t] = cur[t] - v; // exclusive block offsets
}

// K2c: add block offsets -> final start offsets in cursor.
__global__ __launch_bounds__(256) void scan_addoff(
    int* __restrict__ cursor, const int* __restrict__ blockSums) {
  const int b = blockIdx.x, t = threadIdx.x;
  const int g = b * SCAN_BPB + t;
  if (g < N_DSTC) cursor[g] += blockSums[b];
}

// ---------------------------------------------------------------------------
// K3: counting-sort pass 2, int4-vectorized. atomicAdd hands out unique slots;
// after this kernel cursor[i] == end offset of bin i.
__global__ __launch_bounds__(256) void reorder_kernel(
    const int4* __restrict__ src4, const int4* __restrict__ dst4,
    int* __restrict__ cursor, int* __restrict__ sorted_src) {
  int i = blockIdx.x * blockDim.x + threadIdx.x;
  if (i < N_EDGES / 4) {
    int4 s = src4[i];
    int4 d = dst4[i];
    int p0 = atomicAdd(&cursor[d.x], 1); sorted_src[p0] = s.x;
    int p1 = atomicAdd(&cursor[d.y], 1); sorted_src[p1] = s.y;
    int p2 = atomicAdd(&cursor[d.z], 1); sorted_src[p2] = s.z;
    int p3 = atomicAdd(&cursor[d.w], 1); sorted_src[p3] = s.w;
  }
}

// ---------------------------------------------------------------------------
// K4: fused gather + mean + GEMV + colsum. One dst row per wave.
// es = lane>>4 (edge subgroup), q = lane&15 (row quadrant, float4 each).
// Inner loop 4-deep unrolled: 16 edges per pass, 4 independent float4 gathers
// in flight per lane (memory-level parallelism vs. R4's 1).
__global__ __launch_bounds__(256, 4) void gather_h(
    const float* __restrict__ x,
    const float* __restrict__ Ww,   // [64][128]
    const float* __restrict__ Wb,   // [64]
    const int*   __restrict__ cursor,      // end offsets after reorder
    const int*   __restrict__ sorted_src,
    float* __restrict__ h,
    float* __restrict__ colsum) {
  __shared__ float Wt[2 * DIM][NCLS + 1];  // Wt[k][c] = Ww[c*128+k]
  __shared__ float colred[4][64];

  const int tid = threadIdx.x;
  for (int idx = tid; idx < NCLS * 2 * DIM; idx += 256) {
    int c = idx >> 7, k = idx & 127;
    Wt[k][c] = Ww[idx];
  }
  __syncthreads();

  const int wv   = tid >> 6;
  const int lane = tid & 63;
  const int es   = lane >> 4;
  const int q    = lane & 15;
  const int waveId = blockIdx.x * 4 + wv;
  const int tw     = gridDim.x * 4;
  const float bias = Wb[lane];
  const float4* x4 = reinterpret_cast<const float4*>(x);

  float4 colacc = make_float4(0.f, 0.f, 0.f, 0.f);

  for (int r = waveId; r < N_DSTC; r += tw) {
    int beg = (r == 0) ? 0 : cursor[r - 1];
    int end = cursor[r];
    int cnt = end - beg;

    float4 a = make_float4(0.f, 0.f, 0.f, 0.f);
    for (int base = 0; base < cnt; base += 64) {
      int rem = cnt - base;
      int mm  = rem < 64 ? rem : 64;
      int idxv = (lane < rem) ? sorted_src[beg + base + lane] : 0;

      int jb = 0;
      // full 16-edge passes: all lanes active, no per-load guard
      for (; jb + 16 <= mm; jb += 16) {
        int s0 = __shfl(idxv, jb + es,      64);
        int s1 = __shfl(idxv, jb + 4 + es,  64);
        int s2 = __shfl(idxv, jb + 8 + es,  64);
        int s3 = __shfl(idxv, jb + 12 + es, 64);
        float4 v0 = x4[s0 * 16 + q];
        float4 v1 = x4[s1 * 16 + q];
        float4 v2 = x4[s2 * 16 + q];
        float4 v3 = x4[s3 * 16 + q];
        a.x += (v0.x + v1.x) + (v2.x + v3.x);
        a.y += (v0.y + v1.y) + (v2.y + v3.y);
        a.z += (v0.z + v1.z) + (v2.z + v3.z);
        a.w += (v0.w + v1.w) + (v2.w + v3.w);
      }
      // tail: 4 edges per step, predicated accumulate, uniform shfl
      for (; jb < mm; jb += 4) {
        int j = jb + es;
        int s0 = __shfl(idxv, j & 63, 64);
        if (j < mm) {
          float4 v = x4[s0 * 16 + q];
          a.x += v.x; a.y += v.y; a.z += v.z; a.w += v.w;
        }
      }
    }
    // reduce across the 4 edge subgroups
    a.x += __shfl_xor(a.x, 16, 64); a.y += __shfl_xor(a.y, 16, 64);
    a.z += __shfl_xor(a.z, 16, 64); a.w += __shfl_xor(a.w, 16, 64);
    a.x += __shfl_xor(a.x, 32, 64); a.y += __shfl_xor(a.y, 32, 64);
    a.z += __shfl_xor(a.z, 32, 64); a.w += __shfl_xor(a.w, 32, 64);

    float inv = 1.0f / fmaxf((float)cnt, 1.0f);
    float4 ym = make_float4(a.x * inv, a.y * inv, a.z * inv, a.w * inv);

    float4 xv = x4[r * 16 + q];   // whole wave reads same 256B row

    if (es == 0) {
      colacc.x += ym.x; colacc.y += ym.y; colacc.z += ym.z; colacc.w += ym.w;
    }

    // GEMV: h[r][lane] = bias + sum_k feat[k]*Wt[k][lane]
    float hacc = bias;
    #pragma unroll
    for (int k = 0; k < DIM; ++k) {
      const int sl = k >> 2;  // es==0 lane holding quadrant k>>2
      float fx = __shfl((k & 3) == 0 ? xv.x : (k & 3) == 1 ? xv.y :
                        (k & 3) == 2 ? xv.z : xv.w, sl, 64);
      float fy = __shfl((k & 3) == 0 ? ym.x : (k & 3) == 1 ? ym.y :
                        (k & 3) == 2 ? ym.z : ym.w, sl, 64);
      hacc = fmaf(fx, Wt[k][lane], hacc);
      hacc = fmaf(fy, Wt[DIM + k][lane], hacc);
    }
    h[r * NCLS + lane] = hacc;
  }

  if (es == 0) {  // lane q owns columns 4q..4q+3
    colred[wv][q * 4 + 0] = colacc.x;
    colred[wv][q * 4 + 1] = colacc.y;
    colred[wv][q * 4 + 2] = colacc.z;
    colred[wv][q * 4 + 3] = colacc.w;
  }
  __syncthreads();
  if (tid < 64) {
    float s = colred[0][tid] + colred[1][tid] + colred[2][tid] + colred[3][tid];
    atomicAdd(&colsum[tid], s);
  }
}

// ---------------------------------------------------------------------------
// K5: reg partial sums + fused finalize (last block writes the scalar).
__global__ __launch_bounds__(256) void reg_final(
    const float* __restrict__ x,
    const float* __restrict__ u_sum,
    const float* __restrict__ colsum,
    float* __restrict__ regacc,
    int*   __restrict__ done,
    float* __restrict__ out_scalar) {
  const int tid  = threadIdx.x;
  const int lane = tid & 63;
  const int waveId     = blockIdx.x * 4 + (tid >> 6);
  const int totalWaves = gridDim.x * 4;
  const float inv_nd = 1.0f / (float)N_DSTC;
  const float mx = colsum[lane] * inv_nd;   // mean_x[lane]

  float acc = 0.0f;
  for (int r = waveId; r < N_SRC; r += totalWaves) {
    float u  = u_sum[r] * inv_nd;           // broadcast
    float xv = x[r * DIM + lane];
    float d  = fmaf(u, xv, -mx);
    acc = fmaf(d, d, acc);
  }
  #pragma unroll
  for (int off = 32; off > 0; off >>= 1)
    acc += __shfl_down(acc, off, 64);
  if (lane == 0) {
    atomicAdd(regacc, acc);
    __threadfence();          // make this wave's add device-visible
  }
  __syncthreads();
  if (tid == 0) {
    int old = atomicAdd(done, 1);
    if (old == (int)gridDim.x - 1) {
      float total = atomicAdd(regacc, 0.0f);   // atomic read at L2 point
      out_scalar[0] = total * (1.0f / ((float)N_SRC * (float)NCLS));
    }
  }
}

// ---------------------------------------------------------------------------
extern "C" void kernel_launch(void* const* d_in, const int* in_sizes, int n_in,
                              void* d_out, int out_size, void* d_ws, size_t ws_size,
                              hipStream_t stream) {
  const float* x     = (const float*)d_in[0];
  // d_in[1] = w : dead (only ones_like(w) is used)
  const float* u_sum = (const float*)d_in[2];
  const float* Ww    = (const float*)d_in[3];
  const float* Wb    = (const float*)d_in[4];
  const int*   src   = (const int*)d_in[5];
  const int*   dst   = (const int*)d_in[6];

  float* out = (float*)d_out;
  int*   wsI = (int*)d_ws;

  int*   hist       = wsI;                        // 50000
  float* colsum     = (float*)(wsI + N_DSTC);     // 64
  float* regacc     = colsum + 64;                // 1
  int*   done       = (int*)(regacc + 1);         // 1
  int*   blockSums  = done + 1;                   // 196
  int*   cursor     = blockSums + SCAN_NB;        // 50000
  int*   sorted_src = cursor + N_DSTC;            // 1,000,000

  // zero hist + colsum + regacc + done (contiguous front region)
  hipMemsetAsync(d_ws, 0, (size_t)(N_DSTC + 64 + 2) * sizeof(int), stream);

  hist_kernel <<<(N_EDGES / 4 + 255) / 256, 256, 0, stream>>>(
      (const int4*)dst, hist);
  scan_local  <<<SCAN_NB, 256, 0, stream>>>(hist, cursor, blockSums);
  scan_top    <<<1, 256, 0, stream>>>(blockSums);
  scan_addoff <<<SCAN_NB, 256, 0, stream>>>(cursor, blockSums);
  reorder_kernel<<<(N_EDGES / 4 + 255) / 256, 256, 0, stream>>>(
      (const int4*)src, (const int4*)dst, cursor, sorted_src);
  gather_h    <<<1024, 256, 0, stream>>>(x, Ww, Wb, cursor, sorted_src, out, colsum);
  reg_final   <<<2048, 256, 0, stream>>>(x, u_sum, colsum, regacc, done,
                                         out + (size_t)N_DSTC * NCLS);
}

// Round 6
// 392.629 us; speedup vs baseline: 1.4161x; 1.4161x over previous
//
#include <hip/hip_runtime.h>

// Problem constants (fixed by reference)
#define N_SRC   100000
#define N_DSTC  50000
#define N_EDGES 1000000
#define DIM     64
#define NCLS    64

#define SCAN_BPB 256                                   // bins per scan block
#define SCAN_NB  ((N_DSTC + SCAN_BPB - 1) / SCAN_BPB)  // 196

#define HIST_BLOCKS ((N_EDGES / 4 + 255) / 256)        // 977
#define REG_BLOCKS  1024
#define GATHER_GRID 1024

// ws layout (4-byte slots), zero region = [0, 50130):
//   hist    [0, 50000)        int
//   colsum  [50000, 50064)    float
//   regA    [50064]           float   Sum (u*x)^2
//   regB    [50065, 50129)    float   Sum_r u_r * x[r][c]
//   doneG   [50129]           int
//   blockSums [50130, 50326)  int   (fully written by scan_local)
//   cursor    [50326, 100326) int   (fully written by scan chain)
//   sorted_src[100326, ...)   int   (fully written by reorder)

// ---------------------------------------------------------------------------
// K1: fused histogram (blocks [0,HIST_BLOCKS)) + reg A/B accumulation
// (blocks [HIST_BLOCKS, HIST_BLOCKS+REG_BLOCKS)). Disjoint independent work.
__global__ __launch_bounds__(256) void hist_reg_kernel(
    const int4*  __restrict__ dst4,
    const float* __restrict__ x,
    const float* __restrict__ u_sum,
    int*   __restrict__ hist,
    float* __restrict__ regA,
    float* __restrict__ regB) {
  __shared__ float redB[4][64];
  __shared__ float redA[4];

  if (blockIdx.x < HIST_BLOCKS) {
    int i = blockIdx.x * blockDim.x + threadIdx.x;
    if (i < N_EDGES / 4) {
      int4 d = dst4[i];
      atomicAdd(&hist[d.x], 1);
      atomicAdd(&hist[d.y], 1);
      atomicAdd(&hist[d.z], 1);
      atomicAdd(&hist[d.w], 1);
    }
    return;
  }

  // reg part: per-lane column c = lane; accA lane-local since
  // A = sum_{r,c} (u_r * x[r][c])^2.
  const int tid  = threadIdx.x;
  const int wv   = tid >> 6;
  const int lane = tid & 63;
  const int waveId     = (blockIdx.x - HIST_BLOCKS) * 4 + wv;
  const int totalWaves = REG_BLOCKS * 4;

  float accA = 0.0f;
  float accB = 0.0f;
  for (int r = waveId; r < N_SRC; r += totalWaves) {
    float u  = u_sum[r];                 // wave-uniform -> broadcast
    float xv = x[r * DIM + lane];
    float t  = u * xv;
    accB += t;
    accA = fmaf(t, t, accA);
  }
  // accA: full wave reduce
  #pragma unroll
  for (int off = 32; off > 0; off >>= 1)
    accA += __shfl_down(accA, off, 64);
  if (lane == 0) redA[wv] = accA;
  redB[wv][lane] = accB;
  __syncthreads();
  if (tid < 64) {
    float b = redB[0][tid] + redB[1][tid] + redB[2][tid] + redB[3][tid];
    atomicAdd(&regB[tid], b);
  }
  if (tid == 0) {
    float a = redA[0] + redA[1] + redA[2] + redA[3];
    atomicAdd(regA, a);
  }
}

// ---------------------------------------------------------------------------
// K2a: per-block exclusive scan of 256 bins; emit block totals.
__global__ __launch_bounds__(256) void scan_local(
    const int* __restrict__ hist, int* __restrict__ cursor,
    int* __restrict__ blockSums) {
  __shared__ int A[256], B[256];
  const int b = blockIdx.x, t = threadIdx.x;
  const int g = b * SCAN_BPB + t;
  int v = (g < N_DSTC) ? hist[g] : 0;
  A[t] = v;
  __syncthreads();
  int* cur = A; int* nxt = B;
  for (int off = 1; off < 256; off <<= 1) {
    int s = cur[t] + ((t >= off) ? cur[t - off] : 0);
    nxt[t] = s;
    __syncthreads();
    int* tmp = cur; cur = nxt; nxt = tmp;
  }
  if (g < N_DSTC) cursor[g] = cur[t] - v;   // exclusive within block
  if (t == 255) blockSums[b] = cur[255];
}

// K2b: each block redundantly scans the 196 block totals in LDS, then adds
// its own block offset to its 256 cursor entries (merges old scan_top+addoff).
__global__ __launch_bounds__(256) void scan_addoff(
    int* __restrict__ cursor, const int* __restrict__ blockSums) {
  __shared__ int A[256], B[256];
  const int b = blockIdx.x, t = threadIdx.x;
  A[t] = (t < SCAN_NB) ? blockSums[t] : 0;
  __syncthreads();
  int* cur = A; int* nxt = B;
  for (int off = 1; off < 256; off <<= 1) {
    int s = cur[t] + ((t >= off) ? cur[t - off] : 0);
    nxt[t] = s;
    __syncthreads();
    int* tmp = cur; cur = nxt; nxt = tmp;
  }
  int off = (b > 0) ? cur[b - 1] : 0;   // exclusive offset of block b
  int g = b * SCAN_BPB + t;
  if (g < N_DSTC) cursor[g] += off;
}

// ---------------------------------------------------------------------------
// K3: counting-sort pass 2, int4-vectorized. After this kernel,
// cursor[i] == end offset of bin i.
__global__ __launch_bounds__(256) void reorder_kernel(
    const int4* __restrict__ src4, const int4* __restrict__ dst4,
    int* __restrict__ cursor, int* __restrict__ sorted_src) {
  int i = blockIdx.x * blockDim.x + threadIdx.x;
  if (i < N_EDGES / 4) {
    int4 s = src4[i];
    int4 d = dst4[i];
    int p0 = atomicAdd(&cursor[d.x], 1); sorted_src[p0] = s.x;
    int p1 = atomicAdd(&cursor[d.y], 1); sorted_src[p1] = s.y;
    int p2 = atomicAdd(&cursor[d.z], 1); sorted_src[p2] = s.z;
    int p3 = atomicAdd(&cursor[d.w], 1); sorted_src[p3] = s.w;
  }
}

// ---------------------------------------------------------------------------
// K4: fused gather + mean + GEMV + colsum + (last block) reg-loss combine.
// One dst row per wave; es = lane>>4 edge subgroup, q = lane&15 row quadrant.
// 2-deep unroll: 8 rows in flight per wave (R4=4 low-fetch, R5=16 thrashed).
__global__ __launch_bounds__(256, 4) void gather_h(
    const float* __restrict__ x,
    const float* __restrict__ Ww,   // [64][128]
    const float* __restrict__ Wb,   // [64]
    const int*   __restrict__ cursor,      // end offsets after reorder
    const int*   __restrict__ sorted_src,
    float* __restrict__ h,
    float* __restrict__ colsum,
    float* __restrict__ regA,
    float* __restrict__ regB,
    int*   __restrict__ doneG,
    float* __restrict__ out_scalar) {
  __shared__ float Wt[2 * DIM][NCLS + 1];  // Wt[k][c] = Ww[c*128+k]
  __shared__ float colred[4][64];
  __shared__ int   lastFlag;

  const int tid = threadIdx.x;
  for (int idx = tid; idx < NCLS * 2 * DIM; idx += 256) {
    int c = idx >> 7, k = idx & 127;
    Wt[k][c] = Ww[idx];
  }
  __syncthreads();

  const int wv   = tid >> 6;
  const int lane = tid & 63;
  const int es   = lane >> 4;
  const int q    = lane & 15;
  const int waveId = blockIdx.x * 4 + wv;
  const int tw     = gridDim.x * 4;
  const float bias = Wb[lane];
  const float4* x4 = reinterpret_cast<const float4*>(x);

  float4 colacc = make_float4(0.f, 0.f, 0.f, 0.f);

  for (int r = waveId; r < N_DSTC; r += tw) {
    int beg = (r == 0) ? 0 : cursor[r - 1];
    int end = cursor[r];
    int cnt = end - beg;

    float4 a = make_float4(0.f, 0.f, 0.f, 0.f);
    for (int base = 0; base < cnt; base += 64) {
      int rem = cnt - base;
      int mm  = rem < 64 ? rem : 64;
      int idxv = (lane < rem) ? sorted_src[beg + base + lane] : 0;

      int jb = 0;
      for (; jb + 8 <= mm; jb += 8) {   // 2 gathers in flight per lane
        int s0 = __shfl(idxv, jb + es,     64);
        int s1 = __shfl(idxv, jb + 4 + es, 64);
        float4 v0 = x4[s0 * 16 + q];
        float4 v1 = x4[s1 * 16 + q];
        a.x += v0.x + v1.x;
        a.y += v0.y + v1.y;
        a.z += v0.z + v1.z;
        a.w += v0.w + v1.w;
      }
      for (; jb < mm; jb += 4) {        // tail: predicated, uniform shfl
        int j = jb + es;
        int s0 = __shfl(idxv, j & 63, 64);
        if (j < mm) {
          float4 v = x4[s0 * 16 + q];
          a.x += v.x; a.y += v.y; a.z += v.z; a.w += v.w;
        }
      }
    }
    // reduce across the 4 edge subgroups
    a.x += __shfl_xor(a.x, 16, 64); a.y += __shfl_xor(a.y, 16, 64);
    a.z += __shfl_xor(a.z, 16, 64); a.w += __shfl_xor(a.w, 16, 64);
    a.x += __shfl_xor(a.x, 32, 64); a.y += __shfl_xor(a.y, 32, 64);
    a.z += __shfl_xor(a.z, 32, 64); a.w += __shfl_xor(a.w, 32, 64);

    float inv = 1.0f / fmaxf((float)cnt, 1.0f);
    float4 ym = make_float4(a.x * inv, a.y * inv, a.z * inv, a.w * inv);

    float4 xv = x4[r * 16 + q];   // whole wave reads same 256B row

    if (es == 0) {
      colacc.x += ym.x; colacc.y += ym.y; colacc.z += ym.z; colacc.w += ym.w;
    }

    float hacc = bias;
    #pragma unroll
    for (int k = 0; k < DIM; ++k) {
      const int sl = k >> 2;
      float fx = __shfl((k & 3) == 0 ? xv.x : (k & 3) == 1 ? xv.y :
                        (k & 3) == 2 ? xv.z : xv.w, sl, 64);
      float fy = __shfl((k & 3) == 0 ? ym.x : (k & 3) == 1 ? ym.y :
                        (k & 3) == 2 ? ym.z : ym.w, sl, 64);
      hacc = fmaf(fx, Wt[k][lane], hacc);
      hacc = fmaf(fy, Wt[DIM + k][lane], hacc);
    }
    h[r * NCLS + lane] = hacc;
  }

  if (es == 0) {  // lane q owns columns 4q..4q+3
    colred[wv][q * 4 + 0] = colacc.x;
    colred[wv][q * 4 + 1] = colacc.y;
    colred[wv][q * 4 + 2] = colacc.z;
    colred[wv][q * 4 + 3] = colacc.w;
  }
  __syncthreads();
  if (tid < 64) {
    float s = colred[0][tid] + colred[1][tid] + colred[2][tid] + colred[3][tid];
    atomicAdd(&colsum[tid], s);
  }

  // ---- last-block reg-loss combine ----
  __syncthreads();
  if (tid == 0) {
    __threadfence();
    int old = atomicAdd(doneG, 1);
    lastFlag = (old == (int)gridDim.x - 1) ? 1 : 0;
  }
  __syncthreads();
  if (lastFlag && tid < 64) {
    const float inv_nd = 1.0f / (float)N_DSTC;
    float cs = atomicAdd(&colsum[tid], 0.0f);   // coherent atomic read
    float bv = atomicAdd(&regB[tid], 0.0f);
    float mx = cs * inv_nd;
    // per-column: N_SRC*mx^2 - 2*inv_nd*mx*B_c
    float p = fmaf((float)N_SRC * mx, mx, -2.0f * inv_nd * mx * bv);
    #pragma unroll
    for (int off = 32; off > 0; off >>= 1)
      p += __shfl_down(p, off, 64);
    if (tid == 0) {
      float av = atomicAdd(regA, 0.0f);
      float total = fmaf(av, inv_nd * inv_nd, p);
      out_scalar[0] = total * (1.0f / ((float)N_SRC * (float)NCLS));
    }
  }
}

// ---------------------------------------------------------------------------
extern "C" void kernel_launch(void* const* d_in, const int* in_sizes, int n_in,
                              void* d_out, int out_size, void* d_ws, size_t ws_size,
                              hipStream_t stream) {
  const float* x     = (const float*)d_in[0];
  // d_in[1] = w : dead (only ones_like(w) is used)
  const float* u_sum = (const float*)d_in[2];
  const float* Ww    = (const float*)d_in[3];
  const float* Wb    = (const float*)d_in[4];
  const int*   src   = (const int*)d_in[5];
  const int*   dst   = (const int*)d_in[6];

  float* out = (float*)d_out;
  int*   wsI = (int*)d_ws;

  int*   hist       = wsI;                        // 50000
  float* colsum     = (float*)(wsI + N_DSTC);     // 64
  float* regA       = colsum + 64;                // 1
  float* regB       = regA + 1;                   // 64
  int*   doneG      = (int*)(regB + 64);          // 1
  int*   blockSums  = doneG + 1;                  // 196
  int*   cursor     = blockSums + SCAN_NB;        // 50000
  int*   sorted_src = cursor + N_DSTC;            // 1,000,000

  // zero: hist + colsum + regA + regB + doneG
  hipMemsetAsync(d_ws, 0, (size_t)(N_DSTC + 64 + 1 + 64 + 1) * sizeof(int), stream);

  hist_reg_kernel<<<HIST_BLOCKS + REG_BLOCKS, 256, 0, stream>>>(
      (const int4*)dst, x, u_sum, hist, regA, regB);
  scan_local  <<<SCAN_NB, 256, 0, stream>>>(hist, cursor, blockSums);
  scan_addoff <<<SCAN_NB, 256, 0, stream>>>(cursor, blockSums);
  reorder_kernel<<<(N_EDGES / 4 + 255) / 256, 256, 0, stream>>>(
      (const int4*)src, (const int4*)dst, cursor, sorted_src);
  gather_h    <<<GATHER_GRID, 256, 0, stream>>>(
      x, Ww, Wb, cursor, sorted_src, out, colsum, regA, regB, doneG,
      out + (size_t)N_DSTC * NCLS);
}